// Round 10
// baseline (286.654 us; speedup 1.0000x reference)
//
#include <hip/hip_runtime.h>

typedef __bf16 bf16;
typedef __attribute__((ext_vector_type(4))) __bf16 bf16x4;
typedef __attribute__((ext_vector_type(8))) __bf16 bf16x8;
typedef __attribute__((ext_vector_type(4))) float f32x4;

#define MFMA(A,B,C) __builtin_amdgcn_mfma_f32_16x16x32_bf16(A,B,C,0,0,0)

#define SEQ 2048
#define EMB 512
#define HD  64
#define MROWS 8192                 // B*S = 4*2048  (R9 bug: had 4096)
#define SCALE 22.627416997969522f  // sqrt(512): scores are divided by E^-0.5
#define NEG_SEED -3.0e4f           // not -inf (fast-math folds inf to poison)

#define NXF (MROWS*512)            // 4,194,304 floats
#define NWF (1536*512)             //   786,432
#define NOF (512*512)              //   262,144

// ---------------------------------------------------------------------------
// Pre-split: x,Wqkv -> bf16 hi/lo; Wout -> bf16. 5120 blocks x 256, 4 floats/thr.
// ---------------------------------------------------------------------------
__global__ __launch_bounds__(256)
void split_kernel(const float* __restrict__ x, const float* __restrict__ Wq,
                  const float* __restrict__ Wo,
                  bf16* __restrict__ Xh, bf16* __restrict__ Xl,
                  bf16* __restrict__ Wh, bf16* __restrict__ Wl,
                  bf16* __restrict__ Wob) {
  const int i = (blockIdx.x * 256 + threadIdx.x) * 4;
  if (i < NXF) {
    f32x4 v = *(const f32x4*)&x[i];
    bf16x4 h, l;
#pragma unroll
    for (int j = 0; j < 4; ++j) { bf16 t = (bf16)v[j]; h[j] = t; l[j] = (bf16)(v[j] - (float)t); }
    *(bf16x4*)&Xh[i] = h; *(bf16x4*)&Xl[i] = l;
  } else if (i < NXF + NWF) {
    const int k = i - NXF;
    f32x4 v = *(const f32x4*)&Wq[k];
    bf16x4 h, l;
#pragma unroll
    for (int j = 0; j < 4; ++j) { bf16 t = (bf16)v[j]; h[j] = t; l[j] = (bf16)(v[j] - (float)t); }
    *(bf16x4*)&Wh[k] = h; *(bf16x4*)&Wl[k] = l;
  } else {
    const int k = i - NXF - NWF;
    f32x4 v = *(const f32x4*)&Wo[k];
    bf16x4 h;
#pragma unroll
    for (int j = 0; j < 4; ++j) h[j] = (bf16)v[j];
    *(bf16x4*)&Wob[k] = h;
  }
}

// ---------------------------------------------------------------------------
// QKV projection on pre-split bf16: 128x64 tiles, XOR-swizzled unpadded LDS,
// 3-MFMA hi/lo. Grid 1536 = 8 XCD x 8 m-blocks x 24 n-tiles; XCD owns a
// contiguous 1024-row stripe (A-slice 2MB + W 3MB ~ L2-resident).
// ---------------------------------------------------------------------------
__global__ __launch_bounds__(256)
void gemm_qkv(const bf16* __restrict__ Xh, const bf16* __restrict__ Xl,
              const bf16* __restrict__ Wh, const bf16* __restrict__ Wl,
              const float* __restrict__ bias,
              bf16* __restrict__ Qh, bf16* __restrict__ Ql,
              bf16* __restrict__ Kh, bf16* __restrict__ Kl,
              bf16* __restrict__ Vt) {
  __shared__ __align__(16) bf16 AhS[128][64], AlS[128][64];  // 16 KB each
  __shared__ __align__(16) bf16 BhS[64][64],  BlS[64][64];   // 8 KB each (48 KB)
  const int tid = threadIdx.x;
  const int lane = tid & 63, wave = tid >> 6;
  const int lin = blockIdx.x;
  const int xcd = lin & 7, w_ = lin >> 3;       // w_ 0..191
  const int m0 = ((w_ & 7) + xcd * 8) * 128;    // 64 m-blocks (8192 rows)
  const int n0 = (w_ >> 3) * 64;                // 24 n-tiles
  const int wm = (wave >> 1) * 64, wn = (wave & 1) * 32;
  const int c = lane & 15, quad = lane >> 4;

  const f32x4 zero = {0.f, 0.f, 0.f, 0.f};
  f32x4 acc[4][2];
#pragma unroll
  for (int mt = 0; mt < 4; ++mt) { acc[mt][0] = zero; acc[mt][1] = zero; }

  for (int k0 = 0; k0 < 512; k0 += 64) {
    __syncthreads();
#pragma unroll
    for (int j = 0; j < 4; ++j) {
      const int id = j * 256 + tid;             // 0..1023
      const int row = id >> 3, c8 = id & 7;
      const int phys = (c8 ^ (row & 7)) * 8;
      *(bf16x8*)&AhS[row][phys] = *(const bf16x8*)&Xh[(size_t)(m0 + row) * 512 + k0 + c8 * 8];
      *(bf16x8*)&AlS[row][phys] = *(const bf16x8*)&Xl[(size_t)(m0 + row) * 512 + k0 + c8 * 8];
    }
#pragma unroll
    for (int j = 0; j < 2; ++j) {
      const int id = j * 256 + tid;             // 0..511
      const int row = id >> 3, c8 = id & 7;
      const int phys = (c8 ^ (row & 7)) * 8;
      *(bf16x8*)&BhS[row][phys] = *(const bf16x8*)&Wh[(size_t)(n0 + row) * 512 + k0 + c8 * 8];
      *(bf16x8*)&BlS[row][phys] = *(const bf16x8*)&Wl[(size_t)(n0 + row) * 512 + k0 + c8 * 8];
    }
    __syncthreads();
#pragma unroll
    for (int ks8 = 0; ks8 < 8; ks8 += 4) {      // ks = {0,32}
      bf16x8 ah[4], al[4], bh[2], bl[2];
#pragma unroll
      for (int mt = 0; mt < 4; ++mt) {
        const int row = wm + mt * 16 + c;
        const int phys = ((ks8 + quad) ^ (row & 7)) * 8;
        ah[mt] = *(bf16x8*)&AhS[row][phys];
        al[mt] = *(bf16x8*)&AlS[row][phys];
      }
#pragma unroll
      for (int nt = 0; nt < 2; ++nt) {
        const int row = wn + nt * 16 + c;
        const int phys = ((ks8 + quad) ^ (row & 7)) * 8;
        bh[nt] = *(bf16x8*)&BhS[row][phys];
        bl[nt] = *(bf16x8*)&BlS[row][phys];
      }
#pragma unroll
      for (int mt = 0; mt < 4; ++mt)
#pragma unroll
        for (int nt = 0; nt < 2; ++nt) {
          acc[mt][nt] = MFMA(ah[mt], bh[nt], acc[mt][nt]);
          acc[mt][nt] = MFMA(al[mt], bh[nt], acc[mt][nt]);
          acc[mt][nt] = MFMA(ah[mt], bl[nt], acc[mt][nt]);
        }
    }
  }

  // epilogue: C/D row = quad*4+r (m), col = c (n)
#pragma unroll
  for (int mt = 0; mt < 4; ++mt) {
#pragma unroll
    for (int nt = 0; nt < 2; ++nt) {
      const int n = n0 + wn + nt * 16 + c;
      const float bv = bias[n];
#pragma unroll
      for (int r = 0; r < 4; ++r) {
        const int m = m0 + wm + mt * 16 + quad * 4 + r;
        float v = acc[mt][nt][r] + bv;
        const int h = n / 192, t = n % 192;
        const size_t bh = (size_t)((m >> 11) * 8 + h);
        const int s = m & 2047;
        if (t < 64) {
          float q = v * SCALE;
          bf16 hi = (bf16)q;
          float lo = q - (float)hi;
          size_t idx = (bh * SEQ + s) * HD + t;
          Qh[idx] = hi; Ql[idx] = (bf16)lo;
        } else if (t < 128) {
          bf16 hi = (bf16)v;
          float lo = v - (float)hi;
          size_t idx = (bh * SEQ + s) * HD + (t - 64);
          Kh[idx] = hi; Kl[idx] = (bf16)lo;
        } else {
          Vt[(bh * HD + (t - 128)) * SEQ + s] = (bf16)v;
        }
      }
    }
  }
}

// ---------------------------------------------------------------------------
// Output projection: A=O (bf16), B=Wob (pre-converted bf16). FP32 OUT.
// Grid 1024 = 8 XCD x 16 m-blocks x 8 n-tiles (8192 rows).
// ---------------------------------------------------------------------------
__global__ __launch_bounds__(256)
void gemm_out(const bf16* __restrict__ A, const bf16* __restrict__ Bm,
              const float* __restrict__ bias, float* __restrict__ C) {
  __shared__ __align__(16) bf16 As[64][72];
  __shared__ __align__(16) bf16 Bs[64][72];
  const int tid  = threadIdx.x;
  const int lane = tid & 63, wave = tid >> 6;
  const int lin = blockIdx.x;
  const int xcd = lin & 7, w_ = lin >> 3;
  const int m0 = ((w_ & 15) + xcd * 16) * 64;
  const int n0 = (w_ >> 4) * 64;
  const int wm = (wave >> 1) * 32, wn = (wave & 1) * 32;
  const int c = lane & 15, quad = lane >> 4;
  const int lr = tid >> 3, lc = (tid & 7) * 8;

  const f32x4 zero = {0.f, 0.f, 0.f, 0.f};
  f32x4 acc[2][2];
  acc[0][0] = zero; acc[0][1] = zero; acc[1][0] = zero; acc[1][1] = zero;

  for (int k0 = 0; k0 < 512; k0 += 64) {
    *(bf16x8*)&As[lr][lc]      = *(const bf16x8*)&A [(size_t)(m0 + lr     ) * 512 + k0 + lc];
    *(bf16x8*)&As[lr + 32][lc] = *(const bf16x8*)&A [(size_t)(m0 + lr + 32) * 512 + k0 + lc];
    *(bf16x8*)&Bs[lr][lc]      = *(const bf16x8*)&Bm[(size_t)(n0 + lr     ) * 512 + k0 + lc];
    *(bf16x8*)&Bs[lr + 32][lc] = *(const bf16x8*)&Bm[(size_t)(n0 + lr + 32) * 512 + k0 + lc];
    __syncthreads();
#pragma unroll
    for (int ks = 0; ks < 64; ks += 32) {
      bf16x8 a0 = *(bf16x8*)&As[wm + c     ][ks + quad * 8];
      bf16x8 a1 = *(bf16x8*)&As[wm + 16 + c][ks + quad * 8];
      bf16x8 b0 = *(bf16x8*)&Bs[wn + c     ][ks + quad * 8];
      bf16x8 b1 = *(bf16x8*)&Bs[wn + 16 + c][ks + quad * 8];
      acc[0][0] = MFMA(a0, b0, acc[0][0]);
      acc[0][1] = MFMA(a0, b1, acc[0][1]);
      acc[1][0] = MFMA(a1, b0, acc[1][0]);
      acc[1][1] = MFMA(a1, b1, acc[1][1]);
    }
    __syncthreads();
  }

#pragma unroll
  for (int mt = 0; mt < 2; ++mt) {
#pragma unroll
    for (int nt = 0; nt < 2; ++nt) {
      const int n = n0 + wn + nt * 16 + c;
      const float bv = bias[n];
#pragma unroll
      for (int r = 0; r < 4; ++r) {
        const int m = m0 + wm + mt * 16 + quad * 4 + r;
        C[(size_t)m * 512 + n] = acc[mt][nt][r] + bv;
      }
    }
  }
}

// ---------------------------------------------------------------------------
// Attention, double softmax, S^T orientation + pass-1 activity bits (R9 logic,
// unchanged): pass-2 wave-ballot skips of score MFMAs/exp; block-level skip
// of K staging for never-needed chunks.
// ---------------------------------------------------------------------------
__global__ __launch_bounds__(256, 4)
void attn_kernel(const bf16* __restrict__ Qh, const bf16* __restrict__ Ql,
                 const bf16* __restrict__ Kh, const bf16* __restrict__ Kl,
                 const bf16* __restrict__ Vt, bf16* __restrict__ O) {
  __shared__ __align__(16) bf16 KhS[2][32][64];
  __shared__ __align__(16) bf16 KlS[2][32][64];
  __shared__ __align__(16) bf16 VtS[2][64][32];
  __shared__ __align__(16) bf16 tls[4][16][40];
  __shared__ unsigned long long needS[4];
  const int tid  = threadIdx.x;
  const int lane = tid & 63, wave = tid >> 6;
  const int c = lane & 15, quad = lane >> 4;
  const int bh = blockIdx.x;
  const int q0 = blockIdx.y * 64 + wave * 16;
  const size_t hoff = (size_t)bh * SEQ * HD;
  const bf16* qh_p = Qh + hoff;
  const bf16* ql_p = Ql + hoff;
  const bf16* kh_p = Kh + hoff;
  const bf16* kl_p = Kl + hoff;
  const bf16* vt_p = Vt + hoff;
  const f32x4 zero = {0.f, 0.f, 0.f, 0.f};

  const int krow = tid >> 3;
  const int kcol = (tid & 7) * 8;
  const int kphy = ((tid & 7) ^ (krow & 7)) * 8;
  const int vrow = tid >> 2;
  const int vcol = (tid & 3) * 8;
  const int vphy = ((tid & 3) ^ (vrow & 3)) * 8;
  const int pc0 = ((0 + quad) ^ (c & 7)) * 8;
  const int pc1 = ((4 + quad) ^ (c & 7)) * 8;
  const int vpc = (quad ^ (c & 3)) * 8;

  bf16x8 qf[2], qlf[2];
#pragma unroll
  for (int t = 0; t < 2; ++t) {
    size_t off = (size_t)(q0 + c) * HD + t * 32 + quad * 8;
    qf[t]  = *(const bf16x8*)&qh_p[off];
    qlf[t] = *(const bf16x8*)&ql_p[off];
  }

  bf16x8 ONES8;
  bf16x4 ones4;
#pragma unroll
  for (int j = 0; j < 8; ++j) ONES8[j] = (bf16)1.0f;
#pragma unroll
  for (int j = 0; j < 4; ++j) ones4[j] = (bf16)1.0f;

  float mr = NEG_SEED, l1 = 0.f;
  unsigned int bits[4] = {0u, 0u, 0u, 0u};

  // ================= pass 1: online (m, L1) + bits =================
  bf16x8 ph, pl, pv;
  ph = *(const bf16x8*)&kh_p[(size_t)krow * HD + kcol];
  pl = *(const bf16x8*)&kl_p[(size_t)krow * HD + kcol];
  *(bf16x8*)&KhS[0][krow][kphy] = ph;
  *(bf16x8*)&KlS[0][krow][kphy] = pl;
  __syncthreads();
  int buf = 0;
  for (int ch = 0; ch < 64; ++ch) {
    if (ch < 63) {
      const size_t k0 = (size_t)(ch + 1) * 32;
      ph = *(const bf16x8*)&kh_p[(k0 + krow) * HD + kcol];
      pl = *(const bf16x8*)&kl_p[(k0 + krow) * HD + kcol];
    }
#pragma unroll
    for (int kt = 0; kt < 2; ++kt) {
      const int row = kt * 16 + c;
      bf16x8 kh0 = *(bf16x8*)&KhS[buf][row][pc0];
      bf16x8 kl0 = *(bf16x8*)&KlS[buf][row][pc0];
      bf16x8 kh1 = *(bf16x8*)&KhS[buf][row][pc1];
      bf16x8 kl1 = *(bf16x8*)&KlS[buf][row][pc1];
      f32x4 sc = zero;
      sc = MFMA(kh0, qf[0],  sc);
      sc = MFMA(kh0, qlf[0], sc);
      sc = MFMA(kl0, qf[0],  sc);
      sc = MFMA(kh1, qf[1],  sc);
      sc = MFMA(kh1, qlf[1], sc);
      sc = MFMA(kl1, qf[1],  sc);
      float cm = fmaxf(fmaxf(sc[0], sc[1]), fmaxf(sc[2], sc[3]));
      const int bi = ch * 2 + kt;
      bool b = cm > mr - 20.f;   // dropped l1 mass <= 2048*e^-20 relative
      if (b) bits[bi >> 5] |= (1u << (bi & 31));
      if (__ballot(b)) {
        if (b) {
          float nm = fmaxf(mr, cm);
          l1 = l1 * __expf(mr - nm) + __expf(sc[0] - nm) + __expf(sc[1] - nm)
                                    + __expf(sc[2] - nm) + __expf(sc[3] - nm);
          mr = nm;
        }
      }
    }
    if (ch < 63) {
      *(bf16x8*)&KhS[buf ^ 1][krow][kphy] = ph;
      *(bf16x8*)&KlS[buf ^ 1][krow][kphy] = pl;
      __syncthreads();
      buf ^= 1;
    }
  }
#pragma unroll
  for (int off = 16; off < 64; off <<= 1) {
    float mo = __shfl_xor(mr, off, 64);
    float lo = __shfl_xor(l1, off, 64);
    float nm = fmaxf(mr, mo);
    l1 = l1 * __expf(mr - nm) + lo * __expf(mo - nm);
    mr = nm;
  }
  const float inv1 = 1.f / l1;

  // block-level K-need mask for pass 2
  {
    unsigned long long wmask = 0;
    for (int ch = 0; ch < 64; ++ch) {
      const int i0 = ch * 2;
      bool need = (((bits[i0 >> 5] >> (i0 & 31)) & 1u) |
                   ((bits[(i0 + 1) >> 5] >> ((i0 + 1) & 31)) & 1u)) != 0u;
      if (__ballot(need)) wmask |= (1ull << ch);
    }
    if (lane == 0) needS[wave] = wmask;
  }
  __syncthreads();
  const unsigned long long bneed = needS[0] | needS[1] | needS[2] | needS[3];

  f32x4 oacc[4]; oacc[0] = zero; oacc[1] = zero; oacc[2] = zero; oacc[3] = zero;
  float l2 = 0.f;

  // ================= pass 2: t = exp(attn1), o += t*V, skip-aware ======
  if (bneed & 1ull) {
    ph = *(const bf16x8*)&kh_p[(size_t)krow * HD + kcol];
    pl = *(const bf16x8*)&kl_p[(size_t)krow * HD + kcol];
    *(bf16x8*)&KhS[0][krow][kphy] = ph;
    *(bf16x8*)&KlS[0][krow][kphy] = pl;
  }
  pv = *(const bf16x8*)&vt_p[(size_t)vrow * SEQ + vcol];
  *(bf16x8*)&VtS[0][vrow][vphy] = pv;
  __syncthreads();
  buf = 0;
  for (int ch = 0; ch < 64; ++ch) {
    bool ldK = false;
    if (ch < 63) {
      const size_t k0 = (size_t)(ch + 1) * 32;
      ldK = (bneed >> (ch + 1)) & 1ull;
      if (ldK) {
        ph = *(const bf16x8*)&kh_p[(k0 + krow) * HD + kcol];
        pl = *(const bf16x8*)&kl_p[(k0 + krow) * HD + kcol];
      }
      pv = *(const bf16x8*)&vt_p[(size_t)vrow * SEQ + k0 + vcol];
    }
    const int i0 = ch * 2;
    const bool b0 = (bits[i0 >> 5] >> (i0 & 31)) & 1u;
    const bool b1 = (bits[(i0 + 1) >> 5] >> ((i0 + 1) & 31)) & 1u;
    const unsigned long long a0 = __ballot(b0);
    const unsigned long long a1 = __ballot(b1);
    bf16x8 tb;
    if (a0 | a1) {
#pragma unroll
      for (int kt = 0; kt < 2; ++kt) {
        const bool bk = kt ? b1 : b0;
        const unsigned long long ak = kt ? a1 : a0;
        bf16x4 t4 = ones4;
        if (ak) {
          const int row = kt * 16 + c;
          bf16x8 kh0 = *(bf16x8*)&KhS[buf][row][pc0];
          bf16x8 kl0 = *(bf16x8*)&KlS[buf][row][pc0];
          bf16x8 kh1 = *(bf16x8*)&KhS[buf][row][pc1];
          bf16x8 kl1 = *(bf16x8*)&KlS[buf][row][pc1];
          f32x4 sc = zero;
          sc = MFMA(kh0, qf[0],  sc);
          sc = MFMA(kh0, qlf[0], sc);
          sc = MFMA(kl0, qf[0],  sc);
          sc = MFMA(kh1, qf[1],  sc);
          sc = MFMA(kh1, qlf[1], sc);
          sc = MFMA(kl1, qf[1],  sc);
          if (bk) {
            float ls = 0.f;
#pragma unroll
            for (int r = 0; r < 4; ++r) {
              float a1v = __expf(sc[r] - mr) * inv1;  // attn1 in [0,1]
              float tv = __expf(a1v);                 // t in [1,e]
              ls += tv;
              t4[r] = (bf16)tv;
            }
            l2 += ls;
          } else {
            l2 += 4.f;   // all t == 1.0f exactly
          }
        } else {
          l2 += 4.f;
        }
        *(bf16x4*)&tls[wave][c][kt * 16 + quad * 4] = t4;
      }
      tb = *(bf16x8*)&tls[wave][c][quad * 8];
    } else {
      tb = ONES8;        // whole chunk: t == 1 exactly
      l2 += 8.f;
    }
#pragma unroll
    for (int dt = 0; dt < 4; ++dt) {
      bf16x8 va = *(bf16x8*)&VtS[buf][dt * 16 + c][vpc];
      oacc[dt] = MFMA(va, tb, oacc[dt]);
    }
    if (ch < 63) {
      if (ldK) {
        *(bf16x8*)&KhS[buf ^ 1][krow][kphy] = ph;
        *(bf16x8*)&KlS[buf ^ 1][krow][kphy] = pl;
      }
      *(bf16x8*)&VtS[buf ^ 1][vrow][vphy] = pv;
      __syncthreads();
      buf ^= 1;
    }
  }

#pragma unroll
  for (int off = 16; off < 64; off <<= 1) l2 += __shfl_xor(l2, off, 64);

  const int b = bh >> 3, h = bh & 7;
  const float rcp = 1.f / l2;
  bf16* orow = &O[((size_t)b * SEQ + q0 + c) * EMB + h * HD];
#pragma unroll
  for (int dt = 0; dt < 4; ++dt) {
    bf16x4 ov;
#pragma unroll
    for (int r = 0; r < 4; ++r) ov[r] = (bf16)(oacc[dt][r] * rcp);
    *(bf16x4*)&orow[dt * 16 + quad * 4] = ov;
  }
}

// ---------------------------------------------------------------------------
extern "C" void kernel_launch(void* const* d_in, const int* in_sizes, int n_in,
                              void* d_out, int out_size, void* d_ws, size_t ws_size,
                              hipStream_t stream) {
  const float* x    = (const float*)d_in[0];
  const float* Wqkv = (const float*)d_in[1];
  const float* bqkv = (const float*)d_in[2];
  const float* Wout = (const float*)d_in[3];
  const float* bout = (const float*)d_in[4];
  float* out = (float*)d_out;

  char* ws = (char*)d_ws;
  const size_t MB = 1024 * 1024;
  bf16* Qh  = (bf16*)(ws +  0 * MB);
  bf16* Ql  = (bf16*)(ws +  8 * MB);
  bf16* Kh  = (bf16*)(ws + 16 * MB);
  bf16* Kl  = (bf16*)(ws + 24 * MB);
  bf16* Vt  = (bf16*)(ws + 32 * MB);
  bf16* Xh  = (bf16*)(ws + 40 * MB);   // dead after gemm_qkv
  bf16* Xl  = (bf16*)(ws + 48 * MB);
  bf16* O   = (bf16*)(ws + 40 * MB);   // aliases Xh (written by attn, later)
  bf16* Wh  = (bf16*)(ws + 56 * MB);
  bf16* Wl  = (bf16*)(ws + 56 * MB + (size_t)NWF * 2);
  bf16* Wob = (bf16*)(ws + 56 * MB + (size_t)NWF * 4);  // ends at 59.5 MB

  split_kernel<<<5120, 256, 0, stream>>>(x, Wqkv, Wout, Xh, Xl, Wh, Wl, Wob);
  gemm_qkv<<<1536, 256, 0, stream>>>(Xh, Xl, Wh, Wl, bqkv, Qh, Ql, Kh, Kl, Vt);
  attn_kernel<<<dim3(32, SEQ / 64), 256, 0, stream>>>(Qh, Ql, Kh, Kl, Vt, O);
  gemm_out<<<1024, 256, 0, stream>>>(O, Wob, bout, out);
}